// Round 1
// 339.101 us; speedup vs baseline: 1.0279x; 1.0279x over previous
//
#include <hip/hip_runtime.h>
#include <cstdio>

// ---------------- problem constants ----------------
constexpr int T  = 4096;       // B*S tokens
constexpr int D  = 1024;       // n_embed
constexpr int M  = 1408;       // n_moe_mlp
constexpr int E  = 8;          // experts

constexpr int TM = 128;        // token-rows per tile
constexpr int TN = 128;        // output cols per tile
constexpr int BK = 64;         // K-step (64: halves barrier count vs 32; m97 config)
constexpr int RCAP = T * 2 + E * TM;  // 9216 padded row capacity
constexpr int MT_MAX = T / TM; // 32 row-tiles max per expert
constexpr int NT_UP = M / TN;  // 11
constexpr int NT_DN = D / TN;  // 8

constexpr int CSTR = 64;       // per-expert counter stride in ints (256 B)
constexpr int TOKB = 16;       // tokens per router block (16 -> 256 router blocks)
constexpr int RTB  = T / TOKB; // 256 router blocks
constexpr int TP_PER_W = (M / 32) * (D / 32) * E;  // 11264 transpose blocks per weight
constexpr int PREP_GRID = RTB + 3 * TP_PER_W;      // 34048

typedef _Float16 half8 __attribute__((ext_vector_type(8)));
typedef _Float16 half4 __attribute__((ext_vector_type(4)));
typedef float    floatx4 __attribute__((ext_vector_type(4)));

// ---------------- ws layout (bytes) ----------------
constexpr size_t OFF_COUNTS = 0;                               // E*CSTR ints
constexpr size_t OFF_BASE   = (size_t)E * CSTR * 4;            // (legacy, unused)
constexpr size_t OFF_PC     = OFF_BASE + 64;
constexpr size_t OFF_TOTAL  = OFF_PC + 64;
constexpr size_t OFF_T2E    = OFF_TOTAL + 64;                  // 2T ints
constexpr size_t OFF_T2POS  = OFF_T2E   + (size_t)2 * T * 4;
constexpr size_t OFF_T2P    = OFF_T2POS + (size_t)2 * T * 4;
constexpr size_t OFF_TLIST  = OFF_T2P   + (size_t)2 * T * 4;   // E*T ints
constexpr size_t OFF_XG     = OFF_TLIST + (size_t)E * T * 4;   // RCAP x D fp16 (reused as Yp)
constexpr size_t OFF_HID    = OFF_XG  + (size_t)RCAP * D * 2;  // RCAP x M fp16
constexpr size_t OFF_WGT    = OFF_HID + (size_t)RCAP * M * 2;  // E x M x D fp16
constexpr size_t OFF_WUT    = OFF_WGT + (size_t)E * M * D * 2;
constexpr size_t OFF_WDT    = OFF_WUT + (size_t)E * M * D * 2; // E x D x M fp16
constexpr size_t WS_NEED    = OFF_WDT + (size_t)E * D * M * 2;

// async global->LDS, 16B per lane. LDS dest = wave-uniform base + lane*16.
__device__ __forceinline__ void gl_lds16(const void* g, void* l) {
  __builtin_amdgcn_global_load_lds(
      (const __attribute__((address_space(1))) unsigned int*)g,
      (__attribute__((address_space(3))) unsigned int*)l, 16, 0, 0);
}

// 8-expert padded prefix: returns base of expert `e`, its padded count, via
// uniform scalar loads (no shared mem, no sync needed).
__device__ __forceinline__ void expert_base_pc(const int* __restrict__ counts,
                                               int e, int& base_e, int& pc_e) {
  int b = 0; base_e = 0; pc_e = 0;
  #pragma unroll
  for (int ee = 0; ee < E; ++ee) {
    int c = counts[ee * CSTR];
    int p = (c + TM - 1) / TM * TM;
    if (ee == e) { base_e = b; pc_e = p; }
    b += p;
  }
}

// ---------------- fused prep: router blocks + weight-transpose blocks ----------
// blocks [0, RTB): router (16 tokens each).  blocks [RTB, RTB+3*TP_PER_W):
// transpose-convert the three weight tensors f32->f16.  Latency-bound router
// overlaps with BW-bound transposes inside one dispatch.
__global__ __launch_bounds__(256) void k_prep(
    const float* __restrict__ x, const float* __restrict__ wgate,
    const float* __restrict__ w_g, const float* __restrict__ w_u,
    const float* __restrict__ w_d,
    _Float16* __restrict__ wgT, _Float16* __restrict__ wuT, _Float16* __restrict__ wdT,
    int* __restrict__ counts, int* __restrict__ tlist,
    int* __restrict__ t2e, int* __restrict__ t2pos, float* __restrict__ t2p) {
  __shared__ float tile[32][33];
  __shared__ int   s_cnt[E];
  __shared__ int   s_base[E];
  __shared__ int   s_e[2 * TOKB];
  __shared__ int   s_pos[2 * TOKB];
  __shared__ float s_p[2 * TOKB];
  int bid = blockIdx.x;

  if (bid < RTB) {
    // ---- router for tokens [bid*TOKB, +TOKB) ----
    int wv = threadIdx.x >> 6, lane = threadIdx.x & 63;
    if (threadIdx.x < E) s_cnt[threadIdx.x] = 0;
    __syncthreads();
    for (int j = 0; j < TOKB / 4; ++j) {
      int tl = wv * (TOKB / 4) + j;
      int t  = bid * TOKB + tl;
      const float* xr = x + (size_t)t * D;
      float acc[E] = {0.f,0.f,0.f,0.f,0.f,0.f,0.f,0.f};
      #pragma unroll
      for (int i = 0; i < D / 64; ++i) {
        int d = i * 64 + lane;
        float xv = xr[d];
        const float4* wr2 = (const float4*)(wgate + (size_t)d * E);
        float4 w0 = wr2[0], w1 = wr2[1];
        acc[0] += xv * w0.x; acc[1] += xv * w0.y; acc[2] += xv * w0.z; acc[3] += xv * w0.w;
        acc[4] += xv * w1.x; acc[5] += xv * w1.y; acc[6] += xv * w1.z; acc[7] += xv * w1.w;
      }
      #pragma unroll
      for (int e = 0; e < E; ++e) {
        #pragma unroll
        for (int off = 32; off; off >>= 1) acc[e] += __shfl_xor(acc[e], off, 64);
      }
      if (lane == 0) {
        int i0 = 0; float s0 = acc[0];
        #pragma unroll
        for (int e = 1; e < E; ++e) if (acc[e] > s0) { s0 = acc[e]; i0 = e; }
        int i1 = -1; float s1 = -1e30f;
        #pragma unroll
        for (int e = 0; e < E; ++e) if (e != i0 && acc[e] > s1) { s1 = acc[e]; i1 = e; }
        float p0 = 1.f / (1.f + expf(s1 - s0));
        float p1 = 1.f - p0;
        int q0 = atomicAdd(&s_cnt[i0], 1);
        int q1 = atomicAdd(&s_cnt[i1], 1);
        s_e[2 * tl]     = i0; s_pos[2 * tl]     = q0; s_p[2 * tl]     = p0;
        s_e[2 * tl + 1] = i1; s_pos[2 * tl + 1] = q1; s_p[2 * tl + 1] = p1;
      }
    }
    __syncthreads();
    if (threadIdx.x < E)
      s_base[threadIdx.x] = atomicAdd(&counts[threadIdx.x * CSTR], s_cnt[threadIdx.x]);
    __syncthreads();
    if (threadIdx.x < 2 * TOKB) {
      int sl = threadIdx.x;
      int e = s_e[sl];
      int pos = s_base[e] + s_pos[sl];
      int t = bid * TOKB + (sl >> 1);
      tlist[e * T + pos] = t;
      t2e[2 * t + (sl & 1)]   = e;
      t2pos[2 * t + (sl & 1)] = pos;
      t2p[2 * t + (sl & 1)]   = s_p[sl];
    }
    return;
  }

  // ---- transpose-convert [E][R][C] f32 -> [E][C][R] f16 ----
  int i = bid - RTB;
  int which = i / TP_PER_W;
  int j = i - which * TP_PER_W;
  const float* src; _Float16* dst; int Rr, Cc;
  if (which == 0)      { src = w_g; dst = wgT; Rr = D; Cc = M; }
  else if (which == 1) { src = w_u; dst = wuT; Rr = D; Cc = M; }
  else                 { src = w_d; dst = wdT; Rr = M; Cc = D; }
  int ctn = Cc / 32, rtn = Rr / 32;
  int e   = j / (ctn * rtn);
  int rem = j - e * (ctn * rtn);
  int rt = rem / ctn, ct = rem - rt * ctn;
  int tr  = threadIdx.x >> 3;
  int tc4 = (threadIdx.x & 7) * 4;
  const float* s = src + ((size_t)e * Rr + rt * 32 + tr) * Cc + ct * 32 + tc4;
  float4 v = *(const float4*)s;
  tile[tr][tc4 + 0] = v.x; tile[tr][tc4 + 1] = v.y;
  tile[tr][tc4 + 2] = v.z; tile[tr][tc4 + 3] = v.w;
  __syncthreads();
  union { _Float16 h[4]; ushort4 u; } o;
  #pragma unroll
  for (int q = 0; q < 4; ++q) o.h[q] = (_Float16)tile[tc4 + q][tr];
  *(ushort4*)(dst + ((size_t)e * Cc + ct * 32 + tr) * Rr + rt * 32 + tc4) = o.u;
}

// ---------------- gather tokens -> fp16, zero pad rows ----------------
__global__ __launch_bounds__(256) void k_gather(
    const float* __restrict__ x, const int* __restrict__ counts,
    const int* __restrict__ tlist, _Float16* __restrict__ Xg) {
  int r = blockIdx.x;
  int b = 0, e = -1, local = 0, cnt = 0;
  #pragma unroll
  for (int ee = 0; ee < E; ++ee) {
    int c = counts[ee * CSTR];
    int p = (c + TM - 1) / TM * TM;
    if (e < 0 && r < b + p) { e = ee; local = r - b; cnt = c; }
    b += p;
  }
  if (e < 0) return;  // beyond padded total
  int d = threadIdx.x * 4;
  union { _Float16 h[4]; ushort4 u; } o;
  if (local < cnt) {
    int t = tlist[e * T + local];
    float4 v = *(const float4*)(x + (size_t)t * D + d);
    o.h[0] = (_Float16)v.x; o.h[1] = (_Float16)v.y;
    o.h[2] = (_Float16)v.z; o.h[3] = (_Float16)v.w;
  } else {
    o.h[0] = (_Float16)0.f; o.h[1] = (_Float16)0.f;
    o.h[2] = (_Float16)0.f; o.h[3] = (_Float16)0.f;
  }
  *(ushort4*)(Xg + (size_t)r * D + d) = o.u;
}

// ---------------- fused gate+up grouped GEMM + SiLU (BK=64) ----------------
// e = blockIdx.x & 7 pins each expert to one XCD for weight L2 residency.
__global__ __launch_bounds__(256, 2) void k_upgate(
    const _Float16* __restrict__ Xg, const _Float16* __restrict__ wgT,
    const _Float16* __restrict__ wuT, _Float16* __restrict__ Hid,
    const int* __restrict__ counts) {
  int lin = blockIdx.x;
  int e = lin & 7;
  int r = lin >> 3;
  int nt = r % NT_UP;
  int mt = r / NT_UP;
  int base_e, pc_e;
  expert_base_pc(counts, e, base_e, pc_e);
  if (mt * TM >= pc_e) return;
  int row0 = base_e + mt * TM;
  int n0 = nt * TN;
  __shared__ _Float16 As[TM * BK];   // 16 KB
  __shared__ _Float16 Bg[TN * BK];   // 16 KB
  __shared__ _Float16 Bu[TN * BK];   // 16 KB
  int tid = threadIdx.x;
  int w = tid >> 6, lane = tid & 63;
  int lrow = lane & 15, quad = lane >> 4;
  int wr = w >> 1, wc = w & 1;
  int sr = lane >> 3, sc = (lane & 7) * 8;   // 8 rows x 8-half chunks per round

  const _Float16* wg_e = wgT + (size_t)e * M * D;
  const _Float16* wu_e = wuT + (size_t)e * M * D;
  // wave w stages its 32 rows of each tile in 4 rounds of 8 rows (1 KB each)
  const _Float16* pA[4]; const _Float16* pG[4]; const _Float16* pU[4];
  char* lA[4]; char* lG[4]; char* lU[4];
  #pragma unroll
  for (int rr = 0; rr < 4; ++rr) {
    int grow = w * 32 + rr * 8 + sr;
    pA[rr] = Xg   + (size_t)(row0 + grow) * D + sc;
    pG[rr] = wg_e + (size_t)(n0   + grow) * D + sc;
    pU[rr] = wu_e + (size_t)(n0   + grow) * D + sc;
    lA[rr] = (char*)As + (w * 4 + rr) * 1024;
    lG[rr] = (char*)Bg + (w * 4 + rr) * 1024;
    lU[rr] = (char*)Bu + (w * 4 + rr) * 1024;
  }

  floatx4 accg[4][4] = {};   // [c][i]
  floatx4 accu[4][4] = {};

  for (int k0 = 0; k0 < D; k0 += BK) {
    #pragma unroll
    for (int rr = 0; rr < 4; ++rr) {
      gl_lds16(pA[rr], lA[rr]);
      gl_lds16(pG[rr], lG[rr]);
      gl_lds16(pU[rr], lU[rr]);
      pA[rr] += BK; pG[rr] += BK; pU[rr] += BK;
    }
    __syncthreads();
    #pragma unroll
    for (int c2 = 0; c2 < 2; ++c2) {
      half8 af[4];
      #pragma unroll
      for (int i = 0; i < 4; ++i)
        af[i] = *(const half8*)&As[(wr * 64 + i * 16 + lrow) * BK + c2 * 32 + quad * 8];
      #pragma unroll
      for (int c = 0; c < 4; ++c) {
        half8 bgc = *(const half8*)&Bg[(wc * 64 + c * 16 + lrow) * BK + c2 * 32 + quad * 8];
        half8 buc = *(const half8*)&Bu[(wc * 64 + c * 16 + lrow) * BK + c2 * 32 + quad * 8];
        #pragma unroll
        for (int i = 0; i < 4; ++i) {
          accg[c][i] = __builtin_amdgcn_mfma_f32_16x16x32_f16(af[i], bgc, accg[c][i], 0, 0, 0);
          accu[c][i] = __builtin_amdgcn_mfma_f32_16x16x32_f16(af[i], buc, accu[c][i], 0, 0, 0);
        }
      }
    }
    __syncthreads();
  }
  #pragma unroll
  for (int c = 0; c < 4; ++c) {
    int col = n0 + wc * 64 + c * 16 + lrow;
    #pragma unroll
    for (int i = 0; i < 4; ++i) {
      int rowb = row0 + wr * 64 + i * 16 + quad * 4;
      #pragma unroll
      for (int reg = 0; reg < 4; ++reg) {
        float g = accg[c][i][reg], u = accu[c][i][reg];
        Hid[(size_t)(rowb + reg) * M + col] = (_Float16)(g / (1.f + expf(-g)) * u);
      }
    }
  }
}

// ---------------- down grouped GEMM -> per-slot rows Yp (BK=64) ------------
__global__ __launch_bounds__(256, 2) void k_down(
    const _Float16* __restrict__ Hid, const _Float16* __restrict__ wdT,
    _Float16* __restrict__ Yp, const int* __restrict__ counts) {
  int lin = blockIdx.x;
  int e = lin & 7;
  int r = lin >> 3;
  int nt = r % NT_DN;
  int mt = r / NT_DN;
  int base_e, pc_e;
  expert_base_pc(counts, e, base_e, pc_e);
  if (mt * TM >= pc_e) return;
  int row0 = base_e + mt * TM;
  int d0 = nt * TN;
  __shared__ _Float16 As[TM * BK];   // 16 KB
  __shared__ _Float16 Bs[TN * BK];   // 16 KB
  int tid = threadIdx.x;
  int w = tid >> 6, lane = tid & 63;
  int lrow = lane & 15, quad = lane >> 4;
  int wr = w >> 1, wc = w & 1;
  int sr = lane >> 3, sc = (lane & 7) * 8;

  const _Float16* wd_e = wdT + (size_t)e * D * M;
  const _Float16* pA[4]; const _Float16* pB[4];
  char* lA[4]; char* lB[4];
  #pragma unroll
  for (int rr = 0; rr < 4; ++rr) {
    int grow = w * 32 + rr * 8 + sr;
    pA[rr] = Hid  + (size_t)(row0 + grow) * M + sc;
    pB[rr] = wd_e + (size_t)(d0   + grow) * M + sc;
    lA[rr] = (char*)As + (w * 4 + rr) * 1024;
    lB[rr] = (char*)Bs + (w * 4 + rr) * 1024;
  }

  floatx4 acc[4][4] = {};

  for (int k0 = 0; k0 < M; k0 += BK) {
    #pragma unroll
    for (int rr = 0; rr < 4; ++rr) {
      gl_lds16(pA[rr], lA[rr]);
      gl_lds16(pB[rr], lB[rr]);
      pA[rr] += BK; pB[rr] += BK;
    }
    __syncthreads();
    #pragma unroll
    for (int c2 = 0; c2 < 2; ++c2) {
      half8 af[4];
      #pragma unroll
      for (int i = 0; i < 4; ++i)
        af[i] = *(const half8*)&As[(wr * 64 + i * 16 + lrow) * BK + c2 * 32 + quad * 8];
      #pragma unroll
      for (int c = 0; c < 4; ++c) {
        half8 bc = *(const half8*)&Bs[(wc * 64 + c * 16 + lrow) * BK + c2 * 32 + quad * 8];
        #pragma unroll
        for (int i = 0; i < 4; ++i)
          acc[c][i] = __builtin_amdgcn_mfma_f32_16x16x32_f16(af[i], bc, acc[c][i], 0, 0, 0);
      }
    }
    __syncthreads();
  }
  #pragma unroll
  for (int c = 0; c < 4; ++c) {
    int col = d0 + wc * 64 + c * 16 + lrow;
    #pragma unroll
    for (int i = 0; i < 4; ++i) {
      int rowb = row0 + wr * 64 + i * 16 + quad * 4;
      #pragma unroll
      for (int reg = 0; reg < 4; ++reg)
        Yp[(size_t)(rowb + reg) * D + col] = (_Float16)acc[c][i][reg];
    }
  }
}

// ---------------- combine: y[t] = p0*Yp[r0] + p1*Yp[r1] ----------------
__global__ __launch_bounds__(256) void k_combine(
    const _Float16* __restrict__ Yp, const int* __restrict__ counts,
    const int* __restrict__ t2e, const int* __restrict__ t2pos,
    const float* __restrict__ t2p, float* __restrict__ out) {
  int t = blockIdx.x;
  int e0 = t2e[2 * t], e1 = t2e[2 * t + 1];
  int b = 0, b0 = 0, b1 = 0;
  #pragma unroll
  for (int ee = 0; ee < E; ++ee) {
    if (ee == e0) b0 = b;
    if (ee == e1) b1 = b;
    int c = counts[ee * CSTR];
    b += (c + TM - 1) / TM * TM;
  }
  int r0 = b0 + t2pos[2 * t];
  int r1 = b1 + t2pos[2 * t + 1];
  float p0 = t2p[2 * t], p1 = t2p[2 * t + 1];
  int d = threadIdx.x * 4;
  half4 h0 = *(const half4*)(Yp + (size_t)r0 * D + d);
  half4 h1 = *(const half4*)(Yp + (size_t)r1 * D + d);
  float4 o;
  o.x = p0 * (float)h0.x + p1 * (float)h1.x;
  o.y = p0 * (float)h0.y + p1 * (float)h1.y;
  o.z = p0 * (float)h0.z + p1 * (float)h1.z;
  o.w = p0 * (float)h0.w + p1 * (float)h1.w;
  *(float4*)(out + (size_t)t * D + d) = o;
}

// ---------------- launch ----------------
extern "C" void kernel_launch(void* const* d_in, const int* in_sizes, int n_in,
                              void* d_out, int out_size, void* d_ws, size_t ws_size,
                              hipStream_t stream) {
  const float* x     = (const float*)d_in[0];
  const float* wgate = (const float*)d_in[1];
  const float* w_g   = (const float*)d_in[2];
  const float* w_u   = (const float*)d_in[3];
  const float* w_d   = (const float*)d_in[4];
  float* out = (float*)d_out;
  char* ws = (char*)d_ws;

  if (ws_size < WS_NEED) {
    fprintf(stderr, "kernel_launch: ws_size=%zu < needed %zu\n", ws_size, WS_NEED);
    return;
  }

  int* counts = (int*)(ws + OFF_COUNTS);
  int* t2e    = (int*)(ws + OFF_T2E);
  int* t2pos  = (int*)(ws + OFF_T2POS);
  float* t2p  = (float*)(ws + OFF_T2P);
  int* tlist  = (int*)(ws + OFF_TLIST);
  _Float16* Xg  = (_Float16*)(ws + OFF_XG);   // later reused as Yp
  _Float16* Hid = (_Float16*)(ws + OFF_HID);
  _Float16* wgT = (_Float16*)(ws + OFF_WGT);
  _Float16* wuT = (_Float16*)(ws + OFF_WUT);
  _Float16* wdT = (_Float16*)(ws + OFF_WDT);

  hipMemsetAsync(counts, 0, (size_t)E * CSTR * 4, stream);

  k_prep<<<PREP_GRID, 256, 0, stream>>>(x, wgate, w_g, w_u, w_d,
                                        wgT, wuT, wdT,
                                        counts, tlist, t2e, t2pos, t2p);
  k_gather<<<RCAP, 256, 0, stream>>>(x, counts, tlist, Xg);
  k_upgate<<<E * MT_MAX * NT_UP, 256, 0, stream>>>(Xg, wgT, wuT, Hid, counts);
  _Float16* Yp = Xg;   // Xg dead; reuse as Yp
  k_down<<<E * MT_MAX * NT_DN, 256, 0, stream>>>(Hid, wdT, Yp, counts);
  k_combine<<<T, 256, 0, stream>>>(Yp, counts, t2e, t2pos, t2p, out);
}